// Round 5
// baseline (288.914 us; speedup 1.0000x reference)
//
#include <hip/hip_runtime.h>

// B=4, N=8192, CIN=256, H=8, D=64, INNER=512, COUT=256. fp32 I/O.
// out[b] = u_x[b] @ Mb[b] + bo via collapsed per-batch 256x256 matrix.
// All GEMMs: split-bf16 MFMA (x = hi + lo, 3 mfma terms, rel err ~2^-16).
// Inputs pre-split to bf16 hi/lo ONCE (prep kernel) so staging is pure copy.
// dots = Kn^T Vn also on MFMA via in-register InstanceNorm + LDS transpose.
// Occupancy: kv_dots/out_kernel are __launch_bounds__(256,4) with grid 1024
// = 4 blocks/CU x 256 CU -> entire grid co-resident (barrier drains overlap).

#define B_    4
#define N_    8192
#define CIN_  256
#define H_    8
#define D_    64
#define INNER_ 512
#define COUT_ 256
#define EPS_  1e-5f

typedef unsigned short ushort_t;
typedef unsigned int   uint_t;
typedef __attribute__((ext_vector_type(8))) short short8;
typedef __attribute__((ext_vector_type(4))) float f32x4;

__device__ __forceinline__ void split_bf16(float x, ushort_t& hi, ushort_t& lo) {
  const uint_t u = __float_as_uint(x);
  const uint_t hr = (u + 0x8000u) & 0xffff0000u;   // round-half-up to bf16
  hi = (ushort_t)(hr >> 16);
  const float l = x - __uint_as_float(hr);          // exact residual
  lo = (ushort_t)((__float_as_uint(l) + 0x8000u) >> 16);
}

__device__ __forceinline__ void cvt8(float4 x, float4 y, uint4& uh, uint4& ul) {
  const float v[8] = {x.x, x.y, x.z, x.w, y.x, y.y, y.z, y.w};
  ushort_t h[8], l[8];
#pragma unroll
  for (int j = 0; j < 8; j++) split_bf16(v[j], h[j], l[j]);
  uh = make_uint4(h[0] | ((uint_t)h[1] << 16), h[2] | ((uint_t)h[3] << 16),
                  h[4] | ((uint_t)h[5] << 16), h[6] | ((uint_t)h[7] << 16));
  ul = make_uint4(l[0] | ((uint_t)l[1] << 16), l[2] | ((uint_t)l[3] << 16),
                  l[4] | ((uint_t)l[5] << 16), l[6] | ((uint_t)l[7] << 16));
}

#define MFMA(A, Bv, C) __builtin_amdgcn_mfma_f32_16x16x32_bf16((A), (Bv), (C), 0, 0, 0)

// ---------------------------------------------------------------------------
// Prep: split u_x (blocks 0..4095) and [Wk;Wv] (blocks 4096..4223) to bf16
// hi/lo; the 128 w-blocks also zero the dots accumulator (stream-ordered
// before kv_dots). Replaces 2 kernels + 1 memset node.
// ---------------------------------------------------------------------------
__global__ __launch_bounds__(256) void prep_all_kernel(
    const float* __restrict__ u_x, const float* __restrict__ Wk,
    const float* __restrict__ Wv, ushort_t* __restrict__ uxH,
    ushort_t* __restrict__ uxL, ushort_t* __restrict__ WkvH,
    ushort_t* __restrict__ WkvL, float* __restrict__ dots)
{
  const int bid = blockIdx.x;
  if (bid < 4096) {
    const size_t base = ((size_t)bid * 256 + threadIdx.x) * 8;
    const float4 x = *(const float4*)(u_x + base);
    const float4 y = *(const float4*)(u_x + base + 4);
    uint4 uh, ul;
    cvt8(x, y, uh, ul);
    *(uint4*)(uxH + base) = uh;
    *(uint4*)(uxL + base) = ul;
  } else {
    const int wb = bid - 4096;  // 0..127
    const size_t base = ((size_t)wb * 256 + threadIdx.x) * 8;  // 0..262143
    const float* src = (base < 131072) ? (Wk + base) : (Wv + base - 131072);
    const float4 x = *(const float4*)(src);
    const float4 y = *(const float4*)(src + 4);
    uint4 uh, ul;
    cvt8(x, y, uh, ul);
    *(uint4*)(WkvH + base) = uh;
    *(uint4*)(WkvL + base) = ul;
    // zero dots: 128 blocks x 256 thr x 4 floats = 131072 floats
    *(float4*)(dots + ((size_t)wb * 256 + threadIdx.x) * 4) =
        make_float4(0.f, 0.f, 0.f, 0.f);
  }
}

// ---------------------------------------------------------------------------
// Kernel 1: per (chunk of 256 rows, h, b): 2 macro-tiles of 128 rows:
//   KV = u_x @ [Wk_h;Wv_h]^T (split-bf16 MFMA, pure-copy staging)
//   InstanceNorm in-register (per-wave cols are exactly one K/V half)
//   transpose normalized bf16 hi/lo -> LDS, dots += Kt.Vt^T on MFMA
// atomicAdd 64x64 dots per (b,h) at end.
// LDS: union(staging 33280 B, Kt/Vt 4x9216 B) = 36864 B; 4 blocks/CU.
// ---------------------------------------------------------------------------
__global__ __launch_bounds__(256, 4) void kv_dots_kernel(
    const ushort_t* __restrict__ uxH, const ushort_t* __restrict__ uxL,
    const ushort_t* __restrict__ WkvH, const ushort_t* __restrict__ WkvL,
    float* __restrict__ dots)
{
  __shared__ __align__(16) char smem[36864];
  ushort_t (*Ah)[130][8] = (ushort_t(*)[130][8])(smem);
  ushort_t (*Al)[130][8] = (ushort_t(*)[130][8])(smem + 8320);
  ushort_t (*Bh)[130][8] = (ushort_t(*)[130][8])(smem + 16640);
  ushort_t (*Bl)[130][8] = (ushort_t(*)[130][8])(smem + 24960);
  ushort_t* KtH = (ushort_t*)(smem);            // [64][72]
  ushort_t* KtL = (ushort_t*)(smem + 9216);
  ushort_t* VtH = (ushort_t*)(smem + 18432);
  ushort_t* VtL = (ushort_t*)(smem + 27648);

  const int t = threadIdx.x;
  const int chunk = blockIdx.x, h = blockIdx.y, b = blockIdx.z;
  const int lane = t & 63, wave = t >> 6;
  const int q = lane >> 4, r = lane & 15;
  const int m0 = (wave >> 1) * 64, n0 = (wave & 1) * 64;
  const int srow = t >> 1, scs = (t & 1) * 16, q0 = (t & 1) * 2;
  const int dstripe = 16 * wave;

  const int wr = (srow < 64) ? (h * 64 + srow) : (512 + h * 64 + srow - 64);
  const ushort_t* bgH = WkvH + (size_t)wr * CIN_ + scs;
  const ushort_t* bgL = WkvL + (size_t)wr * CIN_ + scs;

  f32x4 dacc[4];
#pragma unroll
  for (int j = 0; j < 4; j++) dacc[j] = (f32x4)0.f;

  for (int mt = 0; mt < 2; mt++) {
    const int r0 = chunk * 256 + mt * 128;
    const ushort_t* agH = uxH + ((size_t)(b * N_) + r0 + srow) * CIN_ + scs;
    const ushort_t* agL = uxL + ((size_t)(b * N_) + r0 + srow) * CIN_ + scs;

    f32x4 acc[4][4];
#pragma unroll
    for (int i = 0; i < 4; i++)
#pragma unroll
      for (int j = 0; j < 4; j++) acc[i][j] = (f32x4)0.f;

    for (int kc = 0; kc < 8; kc++) {
      *(uint4*)&Ah[q0][srow][0]     = *(const uint4*)(agH + kc * 32);
      *(uint4*)&Ah[q0 + 1][srow][0] = *(const uint4*)(agH + kc * 32 + 8);
      *(uint4*)&Al[q0][srow][0]     = *(const uint4*)(agL + kc * 32);
      *(uint4*)&Al[q0 + 1][srow][0] = *(const uint4*)(agL + kc * 32 + 8);
      *(uint4*)&Bh[q0][srow][0]     = *(const uint4*)(bgH + kc * 32);
      *(uint4*)&Bh[q0 + 1][srow][0] = *(const uint4*)(bgH + kc * 32 + 8);
      *(uint4*)&Bl[q0][srow][0]     = *(const uint4*)(bgL + kc * 32);
      *(uint4*)&Bl[q0 + 1][srow][0] = *(const uint4*)(bgL + kc * 32 + 8);
      __syncthreads();
      short8 ahf[4], alf[4];
#pragma unroll
      for (int mi = 0; mi < 4; mi++) {
        ahf[mi] = *(const short8*)&Ah[q][m0 + 16 * mi + r][0];
        alf[mi] = *(const short8*)&Al[q][m0 + 16 * mi + r][0];
      }
#pragma unroll
      for (int nj = 0; nj < 4; nj++) {
        const short8 bhv = *(const short8*)&Bh[q][n0 + 16 * nj + r][0];
        const short8 blv = *(const short8*)&Bl[q][n0 + 16 * nj + r][0];
#pragma unroll
        for (int mi = 0; mi < 4; mi++) {
          acc[mi][nj] = MFMA(ahf[mi], bhv, acc[mi][nj]);
          acc[mi][nj] = MFMA(alf[mi], bhv, acc[mi][nj]);
          acc[mi][nj] = MFMA(ahf[mi], blv, acc[mi][nj]);
        }
      }
      __syncthreads();
    }

    // ---- InstanceNorm in-register (stats over 64 cols = nj-sum + quad shfl)
    float mean[4][4], inv[4][4];
#pragma unroll
    for (int mi = 0; mi < 4; mi++)
#pragma unroll
      for (int reg = 0; reg < 4; reg++) {
        float rs = 0.f, rq = 0.f;
#pragma unroll
        for (int nj = 0; nj < 4; nj++) {
          const float v = acc[mi][nj][reg];
          rs += v;
          rq = fmaf(v, v, rq);
        }
#pragma unroll
        for (int msk = 1; msk < 16; msk <<= 1) {
          rs += __shfl_xor(rs, msk, 64);
          rq += __shfl_xor(rq, msk, 64);
        }
        const float m = rs * (1.f / 64.f);
        const float var = fmaxf(rq * (1.f / 64.f) - m * m, 0.f);
        mean[mi][reg] = m;
        inv[mi][reg] = rsqrtf(var + EPS_);
      }
#pragma unroll
    for (int mi = 0; mi < 4; mi++)
#pragma unroll
      for (int nj = 0; nj < 4; nj++)
#pragma unroll
        for (int reg = 0; reg < 4; reg++)
          acc[mi][nj][reg] = (acc[mi][nj][reg] - mean[mi][reg]) * inv[mi][reg];

    // ---- two 64-row halves: transpose to LDS (bf16 hi/lo), dots MFMA
    for (int p = 0; p < 2; p++) {
      if ((wave >> 1) == p) {
        ushort_t* Hd = (wave & 1) ? VtH : KtH;
        ushort_t* Ld = (wave & 1) ? VtL : KtL;
#pragma unroll
        for (int nj = 0; nj < 4; nj++) {
          const int d = 16 * nj + r;
#pragma unroll
          for (int mi = 0; mi < 4; mi++) {
            const int nb = 16 * mi + 4 * q;
            ushort_t hh[4], ll[4];
#pragma unroll
            for (int reg = 0; reg < 4; reg++)
              split_bf16(acc[mi][nj][reg], hh[reg], ll[reg]);
            uint2 ph, pl;
            ph.x = hh[0] | ((uint_t)hh[1] << 16);
            ph.y = hh[2] | ((uint_t)hh[3] << 16);
            pl.x = ll[0] | ((uint_t)ll[1] << 16);
            pl.y = ll[2] | ((uint_t)ll[3] << 16);
            *(uint2*)&Hd[d * 72 + nb] = ph;
            *(uint2*)&Ld[d * 72 + nb] = pl;
          }
        }
      }
      __syncthreads();
#pragma unroll
      for (int ks = 0; ks < 2; ks++) {
        const short8 aH = *(const short8*)&KtH[(dstripe + r) * 72 + ks * 32 + q * 8];
        const short8 aL = *(const short8*)&KtL[(dstripe + r) * 72 + ks * 32 + q * 8];
#pragma unroll
        for (int ej = 0; ej < 4; ej++) {
          const short8 bH = *(const short8*)&VtH[(16 * ej + r) * 72 + ks * 32 + q * 8];
          const short8 bL = *(const short8*)&VtL[(16 * ej + r) * 72 + ks * 32 + q * 8];
          dacc[ej] = MFMA(aH, bH, dacc[ej]);
          dacc[ej] = MFMA(aL, bH, dacc[ej]);
          dacc[ej] = MFMA(aH, bL, dacc[ej]);
        }
      }
      __syncthreads();
    }
  }

  float* dg = dots + ((size_t)(b * H_ + h)) * 4096;
#pragma unroll
  for (int ej = 0; ej < 4; ej++)
#pragma unroll
    for (int reg = 0; reg < 4; reg++)
      atomicAdd(&dg[(dstripe + 4 * q + reg) * 64 + 16 * ej + r], dacc[ej][reg]);
}

// ---------------------------------------------------------------------------
// Kernel 2a: S[b][hd][o] = sum_e dots[b,h,d,e] * Wo[o, h*64+e]
// ---------------------------------------------------------------------------
__global__ __launch_bounds__(256) void s_kernel(
    const float* __restrict__ dots, const float* __restrict__ Wo,
    float* __restrict__ S)
{
  const int blk = blockIdx.x;  // b*512 + hd
  const int b = blk >> 9, hd = blk & 511, h = hd >> 6;
  __shared__ float drow[64];
  const int t = threadIdx.x;
  if (t < 64) drow[t] = dots[((size_t)(b * H_ + h)) * 4096 + (hd & 63) * 64 + t];
  __syncthreads();
  const float* wp = Wo + (size_t)t * INNER_ + h * 64;
  float acc = 0.f;
#pragma unroll
  for (int e = 0; e < 64; e += 4) {
    const float4 w = *(const float4*)(wp + e);
    acc = fmaf(drow[e + 0], w.x, acc);
    acc = fmaf(drow[e + 1], w.y, acc);
    acc = fmaf(drow[e + 2], w.z, acc);
    acc = fmaf(drow[e + 3], w.w, acc);
  }
  S[((size_t)(b * INNER_) + hd) * COUT_ + t] = acc;
}

// ---------------------------------------------------------------------------
// Kernel 2b: partial Mb over hd-chunks of 128 (grid: 16 c-tiles x 4 b x 4 s)
// ---------------------------------------------------------------------------
__global__ __launch_bounds__(256) void mb_part_kernel(
    const float* __restrict__ Wq, const float* __restrict__ S,
    float* __restrict__ Mbp)
{
  __shared__ __align__(16) float wql[128][16];
  const int c0 = blockIdx.x * 16, b = blockIdx.y, s = blockIdx.z;
  const int t = threadIdx.x;
#pragma unroll
  for (int i = 0; i < 8; i++) {
    const int idx = i * 256 + t;  // 0..2047
    wql[idx >> 4][idx & 15] = Wq[(size_t)(s * 128 + (idx >> 4)) * CIN_ + c0 + (idx & 15)];
  }
  __syncthreads();
  float acc[16];
#pragma unroll
  for (int cp = 0; cp < 16; cp++) acc[cp] = 0.f;
  const float* sp = S + ((size_t)(b * INNER_) + s * 128) * COUT_ + t;
  for (int hd = 0; hd < 128; hd++) {
    const float sv = sp[(size_t)hd * COUT_];
#pragma unroll
    for (int g = 0; g < 4; g++) {
      const float4 w = *(const float4*)&wql[hd][g * 4];
      acc[g * 4 + 0] = fmaf(w.x, sv, acc[g * 4 + 0]);
      acc[g * 4 + 1] = fmaf(w.y, sv, acc[g * 4 + 1]);
      acc[g * 4 + 2] = fmaf(w.z, sv, acc[g * 4 + 2]);
      acc[g * 4 + 3] = fmaf(w.w, sv, acc[g * 4 + 3]);
    }
  }
#pragma unroll
  for (int cp = 0; cp < 16; cp++)
    Mbp[(((size_t)s * 4 + b) * CIN_ + c0 + cp) * COUT_ + t] = acc[cp];
}

// ---------------------------------------------------------------------------
// Kernel 2c: merge 4 partials, scale 1/N, split bf16, write transposed Mbt.
// ---------------------------------------------------------------------------
__global__ __launch_bounds__(256) void mb_merge_kernel(
    const float* __restrict__ Mbp, ushort_t* __restrict__ MbtH,
    ushort_t* __restrict__ MbtL)
{
  const int c0 = blockIdx.x * 16, b = blockIdx.y;
  const int o = threadIdx.x;
#pragma unroll
  for (int cp = 0; cp < 16; cp++) {
    const int c = c0 + cp;
    float v = 0.f;
#pragma unroll
    for (int s = 0; s < 4; s++)
      v += Mbp[(((size_t)s * 4 + b) * CIN_ + c) * COUT_ + o];
    v *= (1.0f / N_);
    ushort_t hi, lo;
    split_bf16(v, hi, lo);
    const size_t off = ((size_t)(b * COUT_) + o) * CIN_ + c;
    MbtH[off] = hi;
    MbtL[off] = lo;
  }
}

// ---------------------------------------------------------------------------
// Kernel 3: out[b,n,o] = sum_c u_x[b,n,c] * Mbt[o][c] + bo[o], split-bf16
// MFMA, 128x128 tile; all staging is pure copies. 4 blocks/CU.
// ---------------------------------------------------------------------------
__global__ __launch_bounds__(256, 4) void out_kernel(
    const ushort_t* __restrict__ uxH, const ushort_t* __restrict__ uxL,
    const ushort_t* __restrict__ MbtH, const ushort_t* __restrict__ MbtL,
    const float* __restrict__ bo, float* __restrict__ out)
{
  __shared__ __align__(16) char smem[33280];
  ushort_t (*Ah)[130][8] = (ushort_t(*)[130][8])(smem);
  ushort_t (*Al)[130][8] = (ushort_t(*)[130][8])(smem + 8320);
  ushort_t (*Bh)[130][8] = (ushort_t(*)[130][8])(smem + 16640);
  ushort_t (*Bl)[130][8] = (ushort_t(*)[130][8])(smem + 24960);

  const int t = threadIdx.x;
  const int r0 = blockIdx.x * 128, o0 = blockIdx.y * 128, b = blockIdx.z;
  const int lane = t & 63, wave = t >> 6;
  const int q = lane >> 4, r = lane & 15;
  const int m0 = (wave >> 1) * 64, n0 = (wave & 1) * 64;
  const int srow = t >> 1, scs = (t & 1) * 16, q0 = (t & 1) * 2;

  const ushort_t* agH = uxH + ((size_t)(b * N_) + r0 + srow) * CIN_ + scs;
  const ushort_t* agL = uxL + ((size_t)(b * N_) + r0 + srow) * CIN_ + scs;
  const ushort_t* bgH = MbtH + ((size_t)(b * COUT_) + o0 + srow) * CIN_ + scs;
  const ushort_t* bgL = MbtL + ((size_t)(b * COUT_) + o0 + srow) * CIN_ + scs;

  f32x4 acc[4][4];
#pragma unroll
  for (int i = 0; i < 4; i++)
#pragma unroll
    for (int j = 0; j < 4; j++) acc[i][j] = (f32x4)0.f;

  for (int kc = 0; kc < 8; kc++) {
    *(uint4*)&Ah[q0][srow][0]     = *(const uint4*)(agH + kc * 32);
    *(uint4*)&Ah[q0 + 1][srow][0] = *(const uint4*)(agH + kc * 32 + 8);
    *(uint4*)&Al[q0][srow][0]     = *(const uint4*)(agL + kc * 32);
    *(uint4*)&Al[q0 + 1][srow][0] = *(const uint4*)(agL + kc * 32 + 8);
    *(uint4*)&Bh[q0][srow][0]     = *(const uint4*)(bgH + kc * 32);
    *(uint4*)&Bh[q0 + 1][srow][0] = *(const uint4*)(bgH + kc * 32 + 8);
    *(uint4*)&Bl[q0][srow][0]     = *(const uint4*)(bgL + kc * 32);
    *(uint4*)&Bl[q0 + 1][srow][0] = *(const uint4*)(bgL + kc * 32 + 8);
    __syncthreads();
    short8 ahf[4], alf[4];
#pragma unroll
    for (int mi = 0; mi < 4; mi++) {
      ahf[mi] = *(const short8*)&Ah[q][m0 + 16 * mi + r][0];
      alf[mi] = *(const short8*)&Al[q][m0 + 16 * mi + r][0];
    }
#pragma unroll
    for (int nj = 0; nj < 4; nj++) {
      const short8 bhv = *(const short8*)&Bh[q][n0 + 16 * nj + r][0];
      const short8 blv = *(const short8*)&Bl[q][n0 + 16 * nj + r][0];
#pragma unroll
      for (int mi = 0; mi < 4; mi++) {
        acc[mi][nj] = MFMA(ahf[mi], bhv, acc[mi][nj]);
        acc[mi][nj] = MFMA(alf[mi], bhv, acc[mi][nj]);
        acc[mi][nj] = MFMA(ahf[mi], blv, acc[mi][nj]);
      }
    }
    __syncthreads();
  }

  float bov[4];
#pragma unroll
  for (int nj = 0; nj < 4; nj++) bov[nj] = bo[o0 + n0 + 16 * nj + r];
#pragma unroll
  for (int mi = 0; mi < 4; mi++)
#pragma unroll
    for (int nj = 0; nj < 4; nj++) {
      const f32x4 v = acc[mi][nj];
#pragma unroll
      for (int reg = 0; reg < 4; reg++) {
        const int row = r0 + m0 + 16 * mi + q * 4 + reg;
        out[((size_t)(b * N_) + row) * COUT_ + o0 + n0 + 16 * nj + r] =
            v[reg] + bov[nj];
      }
    }
}

extern "C" void kernel_launch(void* const* d_in, const int* in_sizes, int n_in,
                              void* d_out, int out_size, void* d_ws, size_t ws_size,
                              hipStream_t stream) {
  const float* u_x = (const float*)d_in[0];
  // d_in[1] = pos_x (unused)
  const float* Wq = (const float*)d_in[2];
  const float* Wk = (const float*)d_in[3];
  const float* Wv = (const float*)d_in[4];
  const float* Wo = (const float*)d_in[5];
  const float* bo = (const float*)d_in[6];
  float* out = (float*)d_out;

  // ws layout
  ushort_t* uxH  = (ushort_t*)d_ws;        // 8388608
  ushort_t* uxL  = uxH + 8388608;          // 8388608
  ushort_t* WkvH = uxL + 8388608;          // 262144
  ushort_t* WkvL = WkvH + 262144;          // 262144
  ushort_t* MbtH = WkvL + 262144;          // 262144
  ushort_t* MbtL = MbtH + 262144;          // 262144
  float* dots = (float*)(MbtL + 262144);   // 131072 floats
  float* S    = dots + 131072;             // 524288 floats
  float* Mbp  = S + 524288;                // 1048576 floats

  prep_all_kernel<<<4224, 256, 0, stream>>>(u_x, Wk, Wv, uxH, uxL, WkvH, WkvL, dots);
  kv_dots_kernel<<<dim3(32, 8, 4), 256, 0, stream>>>(uxH, uxL, WkvH, WkvL, dots);
  s_kernel<<<2048, 256, 0, stream>>>(dots, Wo, S);
  mb_part_kernel<<<dim3(16, 4, 4), 256, 0, stream>>>(Wq, S, Mbp);
  mb_merge_kernel<<<dim3(16, 4), 256, 0, stream>>>(Mbp, MbtH, MbtL);
  out_kernel<<<dim3(64, 2, 4), 256, 0, stream>>>(uxH, uxL, MbtH, MbtL, bo, out);
}

// Round 6
// 231.037 us; speedup vs baseline: 1.2505x; 1.2505x over previous
//
#include <hip/hip_runtime.h>

// B=4, N=8192, CIN=256, H=8, D=64, INNER=512, COUT=256. fp32 I/O.
// out[b] = u_x[b] @ Mb[b] + bo via collapsed per-batch 256x256 matrix.
// All GEMMs: split-bf16 MFMA (x = hi + lo, 3 mfma terms, rel err ~2^-16).
// Inputs pre-split to bf16 hi/lo ONCE (prep kernel) so staging is pure copy.
// dots = Kn^T Vn also on MFMA via in-register InstanceNorm + LDS transpose.
// kv_dots: __launch_bounds__(256,2) — (256,4) spills (r5: VGPR 64, 270 MB
// scratch traffic, 150 us). Double-buffered staging: 1 barrier/kc, loads
// overlap MFMA. LDS 66560 B -> 2 blocks/CU (133 KB/CU).

#define B_    4
#define N_    8192
#define CIN_  256
#define H_    8
#define D_    64
#define INNER_ 512
#define COUT_ 256
#define EPS_  1e-5f

typedef unsigned short ushort_t;
typedef unsigned int   uint_t;
typedef __attribute__((ext_vector_type(8))) short short8;
typedef __attribute__((ext_vector_type(4))) float f32x4;

__device__ __forceinline__ void split_bf16(float x, ushort_t& hi, ushort_t& lo) {
  const uint_t u = __float_as_uint(x);
  const uint_t hr = (u + 0x8000u) & 0xffff0000u;   // round-half-up to bf16
  hi = (ushort_t)(hr >> 16);
  const float l = x - __uint_as_float(hr);          // exact residual
  lo = (ushort_t)((__float_as_uint(l) + 0x8000u) >> 16);
}

__device__ __forceinline__ void cvt8(float4 x, float4 y, uint4& uh, uint4& ul) {
  const float v[8] = {x.x, x.y, x.z, x.w, y.x, y.y, y.z, y.w};
  ushort_t h[8], l[8];
#pragma unroll
  for (int j = 0; j < 8; j++) split_bf16(v[j], h[j], l[j]);
  uh = make_uint4(h[0] | ((uint_t)h[1] << 16), h[2] | ((uint_t)h[3] << 16),
                  h[4] | ((uint_t)h[5] << 16), h[6] | ((uint_t)h[7] << 16));
  ul = make_uint4(l[0] | ((uint_t)l[1] << 16), l[2] | ((uint_t)l[3] << 16),
                  l[4] | ((uint_t)l[5] << 16), l[6] | ((uint_t)l[7] << 16));
}

#define MFMA(A, Bv, C) __builtin_amdgcn_mfma_f32_16x16x32_bf16((A), (Bv), (C), 0, 0, 0)

// ---------------------------------------------------------------------------
// Prep: split u_x (blocks 0..4095) and [Wk;Wv] (blocks 4096..4223) to bf16
// hi/lo; the 128 w-blocks also zero the dots accumulator.
// ---------------------------------------------------------------------------
__global__ __launch_bounds__(256) void prep_all_kernel(
    const float* __restrict__ u_x, const float* __restrict__ Wk,
    const float* __restrict__ Wv, ushort_t* __restrict__ uxH,
    ushort_t* __restrict__ uxL, ushort_t* __restrict__ WkvH,
    ushort_t* __restrict__ WkvL, float* __restrict__ dots)
{
  const int bid = blockIdx.x;
  if (bid < 4096) {
    const size_t base = ((size_t)bid * 256 + threadIdx.x) * 8;
    const float4 x = *(const float4*)(u_x + base);
    const float4 y = *(const float4*)(u_x + base + 4);
    uint4 uh, ul;
    cvt8(x, y, uh, ul);
    *(uint4*)(uxH + base) = uh;
    *(uint4*)(uxL + base) = ul;
  } else {
    const int wb = bid - 4096;  // 0..127
    const size_t base = ((size_t)wb * 256 + threadIdx.x) * 8;  // 0..262143
    const float* src = (base < 131072) ? (Wk + base) : (Wv + base - 131072);
    const float4 x = *(const float4*)(src);
    const float4 y = *(const float4*)(src + 4);
    uint4 uh, ul;
    cvt8(x, y, uh, ul);
    *(uint4*)(WkvH + base) = uh;
    *(uint4*)(WkvL + base) = ul;
    *(float4*)(dots + ((size_t)wb * 256 + threadIdx.x) * 4) =
        make_float4(0.f, 0.f, 0.f, 0.f);
  }
}

// ---------------------------------------------------------------------------
// Kernel 1: per (chunk of 256 rows, h, b): 2 macro-tiles of 128 rows:
//   KV = u_x @ [Wk_h;Wv_h]^T (split-bf16 MFMA, double-buffered staging)
//   InstanceNorm in-register, transpose bf16 hi/lo -> LDS, dots MFMA.
// LDS: stage[2] x 33280 B = 66560 B; Kt/Vt (36864 B) overlays stage area.
// ---------------------------------------------------------------------------
__global__ __launch_bounds__(256, 2) void kv_dots_kernel(
    const ushort_t* __restrict__ uxH, const ushort_t* __restrict__ uxL,
    const ushort_t* __restrict__ WkvH, const ushort_t* __restrict__ WkvL,
    float* __restrict__ dots)
{
  __shared__ __align__(16) char smem[66560];
  // stage s (s=0,1): base smem + s*33280; within: Ah +0, Al +8320,
  // Bh +16640, Bl +24960; each ushort[4][130][8].
  ushort_t* KtH = (ushort_t*)(smem);            // [64][72] overlay
  ushort_t* KtL = (ushort_t*)(smem + 9216);
  ushort_t* VtH = (ushort_t*)(smem + 18432);
  ushort_t* VtL = (ushort_t*)(smem + 27648);

  const int t = threadIdx.x;
  const int chunk = blockIdx.x, h = blockIdx.y, b = blockIdx.z;
  const int lane = t & 63, wave = t >> 6;
  const int q = lane >> 4, r = lane & 15;
  const int m0 = (wave >> 1) * 64, n0 = (wave & 1) * 64;
  const int srow = t >> 1, scs = (t & 1) * 16, q0 = (t & 1) * 2;
  const int dstripe = 16 * wave;

  const int wr = (srow < 64) ? (h * 64 + srow) : (512 + h * 64 + srow - 64);
  const ushort_t* bgH = WkvH + (size_t)wr * CIN_ + scs;
  const ushort_t* bgL = WkvL + (size_t)wr * CIN_ + scs;

  f32x4 dacc[4];
#pragma unroll
  for (int j = 0; j < 4; j++) dacc[j] = (f32x4)0.f;

  for (int mt = 0; mt < 2; mt++) {
    const int r0 = chunk * 256 + mt * 128;
    const ushort_t* agH = uxH + ((size_t)(b * N_) + r0 + srow) * CIN_ + scs;
    const ushort_t* agL = uxL + ((size_t)(b * N_) + r0 + srow) * CIN_ + scs;

    f32x4 acc[4][4];
#pragma unroll
    for (int i = 0; i < 4; i++)
#pragma unroll
      for (int j = 0; j < 4; j++) acc[i][j] = (f32x4)0.f;

    // ---- preload kc=0 into stage 0
    {
      const uint4 a0 = *(const uint4*)(agH);
      const uint4 a1 = *(const uint4*)(agH + 8);
      const uint4 l0 = *(const uint4*)(agL);
      const uint4 l1 = *(const uint4*)(agL + 8);
      const uint4 b0 = *(const uint4*)(bgH);
      const uint4 b1 = *(const uint4*)(bgH + 8);
      const uint4 c0 = *(const uint4*)(bgL);
      const uint4 c1 = *(const uint4*)(bgL + 8);
      ushort_t (*Ah)[130][8] = (ushort_t(*)[130][8])(smem);
      ushort_t (*Al)[130][8] = (ushort_t(*)[130][8])(smem + 8320);
      ushort_t (*Bh)[130][8] = (ushort_t(*)[130][8])(smem + 16640);
      ushort_t (*Bl)[130][8] = (ushort_t(*)[130][8])(smem + 24960);
      *(uint4*)&Ah[q0][srow][0] = a0;  *(uint4*)&Ah[q0 + 1][srow][0] = a1;
      *(uint4*)&Al[q0][srow][0] = l0;  *(uint4*)&Al[q0 + 1][srow][0] = l1;
      *(uint4*)&Bh[q0][srow][0] = b0;  *(uint4*)&Bh[q0 + 1][srow][0] = b1;
      *(uint4*)&Bl[q0][srow][0] = c0;  *(uint4*)&Bl[q0 + 1][srow][0] = c1;
    }
    __syncthreads();

#pragma unroll 2
    for (int kc = 0; kc < 8; kc++) {
      const int cur = kc & 1, nxt = cur ^ 1;
      // issue next-slab global loads (overlap with MFMA below)
      uint4 a0, a1, l0, l1, b0, b1, c0, c1;
      if (kc < 7) {
        const int off = (kc + 1) * 32;
        a0 = *(const uint4*)(agH + off);  a1 = *(const uint4*)(agH + off + 8);
        l0 = *(const uint4*)(agL + off);  l1 = *(const uint4*)(agL + off + 8);
        b0 = *(const uint4*)(bgH + off);  b1 = *(const uint4*)(bgH + off + 8);
        c0 = *(const uint4*)(bgL + off);  c1 = *(const uint4*)(bgL + off + 8);
      }
      char* sc = smem + cur * 33280;
      ushort_t (*Ah)[130][8] = (ushort_t(*)[130][8])(sc);
      ushort_t (*Al)[130][8] = (ushort_t(*)[130][8])(sc + 8320);
      ushort_t (*Bh)[130][8] = (ushort_t(*)[130][8])(sc + 16640);
      ushort_t (*Bl)[130][8] = (ushort_t(*)[130][8])(sc + 24960);
      short8 ahf[4], alf[4];
#pragma unroll
      for (int mi = 0; mi < 4; mi++) {
        ahf[mi] = *(const short8*)&Ah[q][m0 + 16 * mi + r][0];
        alf[mi] = *(const short8*)&Al[q][m0 + 16 * mi + r][0];
      }
#pragma unroll
      for (int nj = 0; nj < 4; nj++) {
        const short8 bhv = *(const short8*)&Bh[q][n0 + 16 * nj + r][0];
        const short8 blv = *(const short8*)&Bl[q][n0 + 16 * nj + r][0];
#pragma unroll
        for (int mi = 0; mi < 4; mi++) {
          acc[mi][nj] = MFMA(ahf[mi], bhv, acc[mi][nj]);
          acc[mi][nj] = MFMA(alf[mi], bhv, acc[mi][nj]);
          acc[mi][nj] = MFMA(ahf[mi], blv, acc[mi][nj]);
        }
      }
      if (kc < 7) {
        char* sn = smem + nxt * 33280;
        ushort_t (*nAh)[130][8] = (ushort_t(*)[130][8])(sn);
        ushort_t (*nAl)[130][8] = (ushort_t(*)[130][8])(sn + 8320);
        ushort_t (*nBh)[130][8] = (ushort_t(*)[130][8])(sn + 16640);
        ushort_t (*nBl)[130][8] = (ushort_t(*)[130][8])(sn + 24960);
        *(uint4*)&nAh[q0][srow][0] = a0;  *(uint4*)&nAh[q0 + 1][srow][0] = a1;
        *(uint4*)&nAl[q0][srow][0] = l0;  *(uint4*)&nAl[q0 + 1][srow][0] = l1;
        *(uint4*)&nBh[q0][srow][0] = b0;  *(uint4*)&nBh[q0 + 1][srow][0] = b1;
        *(uint4*)&nBl[q0][srow][0] = c0;  *(uint4*)&nBl[q0 + 1][srow][0] = c1;
      }
      __syncthreads();
    }

    // ---- InstanceNorm in-register (stats over 64 cols = nj-sum + quad shfl)
    float mean[4][4], inv[4][4];
#pragma unroll
    for (int mi = 0; mi < 4; mi++)
#pragma unroll
      for (int reg = 0; reg < 4; reg++) {
        float rs = 0.f, rq = 0.f;
#pragma unroll
        for (int nj = 0; nj < 4; nj++) {
          const float v = acc[mi][nj][reg];
          rs += v;
          rq = fmaf(v, v, rq);
        }
#pragma unroll
        for (int msk = 1; msk < 16; msk <<= 1) {
          rs += __shfl_xor(rs, msk, 64);
          rq += __shfl_xor(rq, msk, 64);
        }
        const float m = rs * (1.f / 64.f);
        const float var = fmaxf(rq * (1.f / 64.f) - m * m, 0.f);
        mean[mi][reg] = m;
        inv[mi][reg] = rsqrtf(var + EPS_);
      }
#pragma unroll
    for (int mi = 0; mi < 4; mi++)
#pragma unroll
      for (int nj = 0; nj < 4; nj++)
#pragma unroll
        for (int reg = 0; reg < 4; reg++)
          acc[mi][nj][reg] = (acc[mi][nj][reg] - mean[mi][reg]) * inv[mi][reg];

    // ---- two 64-row halves: transpose to LDS (bf16 hi/lo), dots MFMA
    for (int p = 0; p < 2; p++) {
      if ((wave >> 1) == p) {
        ushort_t* Hd = (wave & 1) ? VtH : KtH;
        ushort_t* Ld = (wave & 1) ? VtL : KtL;
#pragma unroll
        for (int nj = 0; nj < 4; nj++) {
          const int d = 16 * nj + r;
#pragma unroll
          for (int mi = 0; mi < 4; mi++) {
            const int nb = 16 * mi + 4 * q;
            ushort_t hh[4], ll[4];
#pragma unroll
            for (int reg = 0; reg < 4; reg++)
              split_bf16(acc[mi][nj][reg], hh[reg], ll[reg]);
            uint2 ph, pl;
            ph.x = hh[0] | ((uint_t)hh[1] << 16);
            ph.y = hh[2] | ((uint_t)hh[3] << 16);
            pl.x = ll[0] | ((uint_t)ll[1] << 16);
            pl.y = ll[2] | ((uint_t)ll[3] << 16);
            *(uint2*)&Hd[d * 72 + nb] = ph;
            *(uint2*)&Ld[d * 72 + nb] = pl;
          }
        }
      }
      __syncthreads();
#pragma unroll
      for (int ks = 0; ks < 2; ks++) {
        const short8 aH = *(const short8*)&KtH[(dstripe + r) * 72 + ks * 32 + q * 8];
        const short8 aL = *(const short8*)&KtL[(dstripe + r) * 72 + ks * 32 + q * 8];
#pragma unroll
        for (int ej = 0; ej < 4; ej++) {
          const short8 bH = *(const short8*)&VtH[(16 * ej + r) * 72 + ks * 32 + q * 8];
          const short8 bL = *(const short8*)&VtL[(16 * ej + r) * 72 + ks * 32 + q * 8];
          dacc[ej] = MFMA(aH, bH, dacc[ej]);
          dacc[ej] = MFMA(aL, bH, dacc[ej]);
          dacc[ej] = MFMA(aH, bL, dacc[ej]);
        }
      }
      __syncthreads();
    }
  }

  float* dg = dots + ((size_t)(b * H_ + h)) * 4096;
#pragma unroll
  for (int ej = 0; ej < 4; ej++)
#pragma unroll
    for (int reg = 0; reg < 4; reg++)
      atomicAdd(&dg[(dstripe + 4 * q + reg) * 64 + 16 * ej + r], dacc[ej][reg]);
}

// ---------------------------------------------------------------------------
// Kernel 2a: S[b][hd][o] = sum_e dots[b,h,d,e] * Wo[o, h*64+e]
// ---------------------------------------------------------------------------
__global__ __launch_bounds__(256) void s_kernel(
    const float* __restrict__ dots, const float* __restrict__ Wo,
    float* __restrict__ S)
{
  const int blk = blockIdx.x;  // b*512 + hd
  const int b = blk >> 9, hd = blk & 511, h = hd >> 6;
  __shared__ float drow[64];
  const int t = threadIdx.x;
  if (t < 64) drow[t] = dots[((size_t)(b * H_ + h)) * 4096 + (hd & 63) * 64 + t];
  __syncthreads();
  const float* wp = Wo + (size_t)t * INNER_ + h * 64;
  float acc = 0.f;
#pragma unroll
  for (int e = 0; e < 64; e += 4) {
    const float4 w = *(const float4*)(wp + e);
    acc = fmaf(drow[e + 0], w.x, acc);
    acc = fmaf(drow[e + 1], w.y, acc);
    acc = fmaf(drow[e + 2], w.z, acc);
    acc = fmaf(drow[e + 3], w.w, acc);
  }
  S[((size_t)(b * INNER_) + hd) * COUT_ + t] = acc;
}

// ---------------------------------------------------------------------------
// Kernel 2b: partial Mb over hd-chunks of 128 (grid: 16 c-tiles x 4 b x 4 s)
// ---------------------------------------------------------------------------
__global__ __launch_bounds__(256) void mb_part_kernel(
    const float* __restrict__ Wq, const float* __restrict__ S,
    float* __restrict__ Mbp)
{
  __shared__ __align__(16) float wql[128][16];
  const int c0 = blockIdx.x * 16, b = blockIdx.y, s = blockIdx.z;
  const int t = threadIdx.x;
#pragma unroll
  for (int i = 0; i < 8; i++) {
    const int idx = i * 256 + t;  // 0..2047
    wql[idx >> 4][idx & 15] = Wq[(size_t)(s * 128 + (idx >> 4)) * CIN_ + c0 + (idx & 15)];
  }
  __syncthreads();
  float acc[16];
#pragma unroll
  for (int cp = 0; cp < 16; cp++) acc[cp] = 0.f;
  const float* sp = S + ((size_t)(b * INNER_) + s * 128) * COUT_ + t;
  for (int hd = 0; hd < 128; hd++) {
    const float sv = sp[(size_t)hd * COUT_];
#pragma unroll
    for (int g = 0; g < 4; g++) {
      const float4 w = *(const float4*)&wql[hd][g * 4];
      acc[g * 4 + 0] = fmaf(w.x, sv, acc[g * 4 + 0]);
      acc[g * 4 + 1] = fmaf(w.y, sv, acc[g * 4 + 1]);
      acc[g * 4 + 2] = fmaf(w.z, sv, acc[g * 4 + 2]);
      acc[g * 4 + 3] = fmaf(w.w, sv, acc[g * 4 + 3]);
    }
  }
#pragma unroll
  for (int cp = 0; cp < 16; cp++)
    Mbp[(((size_t)s * 4 + b) * CIN_ + c0 + cp) * COUT_ + t] = acc[cp];
}

// ---------------------------------------------------------------------------
// Kernel 2c: merge 4 partials, scale 1/N, split bf16, write transposed Mbt.
// ---------------------------------------------------------------------------
__global__ __launch_bounds__(256) void mb_merge_kernel(
    const float* __restrict__ Mbp, ushort_t* __restrict__ MbtH,
    ushort_t* __restrict__ MbtL)
{
  const int c0 = blockIdx.x * 16, b = blockIdx.y;
  const int o = threadIdx.x;
#pragma unroll
  for (int cp = 0; cp < 16; cp++) {
    const int c = c0 + cp;
    float v = 0.f;
#pragma unroll
    for (int s = 0; s < 4; s++)
      v += Mbp[(((size_t)s * 4 + b) * CIN_ + c) * COUT_ + o];
    v *= (1.0f / N_);
    ushort_t hi, lo;
    split_bf16(v, hi, lo);
    const size_t off = ((size_t)(b * COUT_) + o) * CIN_ + c;
    MbtH[off] = hi;
    MbtL[off] = lo;
  }
}

// ---------------------------------------------------------------------------
// Kernel 3: out[b,n,o] = sum_c u_x[b,n,c] * Mbt[o][c] + bo[o], split-bf16
// MFMA, 128x128 tile; staging pure copies. (256,4): live set ~110 fits the
// 128-reg budget (no spill signature in r5).
// ---------------------------------------------------------------------------
__global__ __launch_bounds__(256, 4) void out_kernel(
    const ushort_t* __restrict__ uxH, const ushort_t* __restrict__ uxL,
    const ushort_t* __restrict__ MbtH, const ushort_t* __restrict__ MbtL,
    const float* __restrict__ bo, float* __restrict__ out)
{
  __shared__ __align__(16) char smem[33280];
  ushort_t (*Ah)[130][8] = (ushort_t(*)[130][8])(smem);
  ushort_t (*Al)[130][8] = (ushort_t(*)[130][8])(smem + 8320);
  ushort_t (*Bh)[130][8] = (ushort_t(*)[130][8])(smem + 16640);
  ushort_t (*Bl)[130][8] = (ushort_t(*)[130][8])(smem + 24960);

  const int t = threadIdx.x;
  const int r0 = blockIdx.x * 128, o0 = blockIdx.y * 128, b = blockIdx.z;
  const int lane = t & 63, wave = t >> 6;
  const int q = lane >> 4, r = lane & 15;
  const int m0 = (wave >> 1) * 64, n0 = (wave & 1) * 64;
  const int srow = t >> 1, scs = (t & 1) * 16, q0 = (t & 1) * 2;

  const ushort_t* agH = uxH + ((size_t)(b * N_) + r0 + srow) * CIN_ + scs;
  const ushort_t* agL = uxL + ((size_t)(b * N_) + r0 + srow) * CIN_ + scs;
  const ushort_t* bgH = MbtH + ((size_t)(b * COUT_) + o0 + srow) * CIN_ + scs;
  const ushort_t* bgL = MbtL + ((size_t)(b * COUT_) + o0 + srow) * CIN_ + scs;

  f32x4 acc[4][4];
#pragma unroll
  for (int i = 0; i < 4; i++)
#pragma unroll
    for (int j = 0; j < 4; j++) acc[i][j] = (f32x4)0.f;

  for (int kc = 0; kc < 8; kc++) {
    *(uint4*)&Ah[q0][srow][0]     = *(const uint4*)(agH + kc * 32);
    *(uint4*)&Ah[q0 + 1][srow][0] = *(const uint4*)(agH + kc * 32 + 8);
    *(uint4*)&Al[q0][srow][0]     = *(const uint4*)(agL + kc * 32);
    *(uint4*)&Al[q0 + 1][srow][0] = *(const uint4*)(agL + kc * 32 + 8);
    *(uint4*)&Bh[q0][srow][0]     = *(const uint4*)(bgH + kc * 32);
    *(uint4*)&Bh[q0 + 1][srow][0] = *(const uint4*)(bgH + kc * 32 + 8);
    *(uint4*)&Bl[q0][srow][0]     = *(const uint4*)(bgL + kc * 32);
    *(uint4*)&Bl[q0 + 1][srow][0] = *(const uint4*)(bgL + kc * 32 + 8);
    __syncthreads();
    short8 ahf[4], alf[4];
#pragma unroll
    for (int mi = 0; mi < 4; mi++) {
      ahf[mi] = *(const short8*)&Ah[q][m0 + 16 * mi + r][0];
      alf[mi] = *(const short8*)&Al[q][m0 + 16 * mi + r][0];
    }
#pragma unroll
    for (int nj = 0; nj < 4; nj++) {
      const short8 bhv = *(const short8*)&Bh[q][n0 + 16 * nj + r][0];
      const short8 blv = *(const short8*)&Bl[q][n0 + 16 * nj + r][0];
#pragma unroll
      for (int mi = 0; mi < 4; mi++) {
        acc[mi][nj] = MFMA(ahf[mi], bhv, acc[mi][nj]);
        acc[mi][nj] = MFMA(alf[mi], bhv, acc[mi][nj]);
        acc[mi][nj] = MFMA(ahf[mi], blv, acc[mi][nj]);
      }
    }
    __syncthreads();
  }

  float bov[4];
#pragma unroll
  for (int nj = 0; nj < 4; nj++) bov[nj] = bo[o0 + n0 + 16 * nj + r];
#pragma unroll
  for (int mi = 0; mi < 4; mi++)
#pragma unroll
    for (int nj = 0; nj < 4; nj++) {
      const f32x4 v = acc[mi][nj];
#pragma unroll
      for (int reg = 0; reg < 4; reg++) {
        const int row = r0 + m0 + 16 * mi + q * 4 + reg;
        out[((size_t)(b * N_) + row) * COUT_ + o0 + n0 + 16 * nj + r] =
            v[reg] + bov[nj];
      }
    }
}

extern "C" void kernel_launch(void* const* d_in, const int* in_sizes, int n_in,
                              void* d_out, int out_size, void* d_ws, size_t ws_size,
                              hipStream_t stream) {
  const float* u_x = (const float*)d_in[0];
  // d_in[1] = pos_x (unused)
  const float* Wq = (const float*)d_in[2];
  const float* Wk = (const float*)d_in[3];
  const float* Wv = (const float*)d_in[4];
  const float* Wo = (const float*)d_in[5];
  const float* bo = (const float*)d_in[6];
  float* out = (float*)d_out;

  // ws layout
  ushort_t* uxH  = (ushort_t*)d_ws;        // 8388608
  ushort_t* uxL  = uxH + 8388608;          // 8388608
  ushort_t* WkvH = uxL + 8388608;          // 262144
  ushort_t* WkvL = WkvH + 262144;          // 262144
  ushort_t* MbtH = WkvL + 262144;          // 262144
  ushort_t* MbtL = MbtH + 262144;          // 262144
  float* dots = (float*)(MbtL + 262144);   // 131072 floats
  float* S    = dots + 131072;             // 524288 floats
  float* Mbp  = S + 524288;                // 1048576 floats

  prep_all_kernel<<<4224, 256, 0, stream>>>(u_x, Wk, Wv, uxH, uxL, WkvH, WkvL, dots);
  kv_dots_kernel<<<dim3(32, 8, 4), 256, 0, stream>>>(uxH, uxL, WkvH, WkvL, dots);
  s_kernel<<<2048, 256, 0, stream>>>(dots, Wo, S);
  mb_part_kernel<<<dim3(16, 4, 4), 256, 0, stream>>>(Wq, S, Mbp);
  mb_merge_kernel<<<dim3(16, 4), 256, 0, stream>>>(Mbp, MbtH, MbtL);
  out_kernel<<<dim3(64, 2, 4), 256, 0, stream>>>(uxH, uxL, MbtH, MbtL, bo, out);
}